// Round 4
// baseline (1005.330 us; speedup 1.0000x reference)
//
#include <hip/hip_runtime.h>
#include <math.h>

#define B_ 512
#define L_ 100
#define D_ 1024
#define POS_DIM_ 50
#define GM 51200
#define GN 1024
#define GK 1024
#define LDA 36   // LDS row stride (halfwords): 18 words/row -> uniform bank spread

typedef _Float16 half8 __attribute__((ext_vector_type(8)));
typedef _Float16 half4 __attribute__((ext_vector_type(4)));
typedef float floatx4 __attribute__((ext_vector_type(4)));

// ---------- fast device math ----------
__device__ __forceinline__ float fast_tanh(float x) {
    float e = __expf(2.0f * x);
    return 1.0f - 2.0f * __builtin_amdgcn_rcpf(e + 1.0f);
}
__device__ __forceinline__ float fast_sigmoid(float x) {
    return __builtin_amdgcn_rcpf(1.0f + __expf(-x));
}

// async global->LDS, 16B per lane; lds base must be wave-uniform
__device__ __forceinline__ void gll16(const void* g, void* l) {
    __builtin_amdgcn_global_load_lds(
        (const __attribute__((address_space(1))) void*)g,
        (__attribute__((address_space(3))) void*)l, 16, 0, 0);
}

// ---------- Kernel 1: docs (masked mean) + f16 hi/lo split of docs ----------
__global__ __launch_bounds__(256) void docs_kernel(
    const float* __restrict__ sent, const int* __restrict__ doc_lens,
    _Float16* __restrict__ docs_hi, _Float16* __restrict__ docs_lo)
{
    int b = blockIdx.x;
    int tid = threadIdx.x;
    int len = doc_lens[b];
    float inv = 1.0f / (float)len;
    const float* p = sent + (size_t)b * L_ * D_ + tid * 4;
    float4 acc = {0.f, 0.f, 0.f, 0.f};
    for (int l = 0; l < len; ++l) {
        float4 v = *(const float4*)(p + (size_t)l * D_);
        acc.x += v.x; acc.y += v.y; acc.z += v.z; acc.w += v.w;
    }
    float a[4] = {acc.x * inv, acc.y * inv, acc.z * inv, acc.w * inv};
    half4 h, lo;
    #pragma unroll
    for (int i = 0; i < 4; ++i) {
        _Float16 hi = (_Float16)a[i];
        h[i] = hi;
        lo[i] = (_Float16)(a[i] - (float)hi);
    }
    *(half4*)(docs_hi + (size_t)b * D_ + tid * 4) = h;
    *(half4*)(docs_lo + (size_t)b * D_ + tid * 4) = lo;
}

// ---------- Kernel 2: tiny embedding dots ----------
__global__ void emb_kernel(const float* __restrict__ abs_emb,
                           const float* __restrict__ rel_emb,
                           const float* __restrict__ abs_w,
                           const float* __restrict__ rel_w,
                           float* __restrict__ abs_p, float* __restrict__ rel_vals)
{
    int t = threadIdx.x;
    if (t < L_) {
        float a = 0.f;
        for (int j = 0; j < POS_DIM_; ++j) a += abs_emb[t * POS_DIM_ + j] * abs_w[j];
        abs_p[t] = a;
    }
    if (t < 10) {
        float r = 0.f;
        for (int j = 0; j < POS_DIM_; ++j) r += rel_emb[t * POS_DIM_ + j] * rel_w[j];
        rel_vals[t] = r;
    }
}

// ---------- Kernel 3: elementwise f16 hi/lo split of fc_w and sal_w ----------
__global__ __launch_bounds__(256) void wsplit_kernel(
    const float* __restrict__ fc_w, const float* __restrict__ sal_w,
    _Float16* __restrict__ fcw_hi, _Float16* __restrict__ fcw_lo,
    _Float16* __restrict__ salw_hi, _Float16* __restrict__ salw_lo)
{
    int id = blockIdx.x * 256 + threadIdx.x;
    int base = id * 4;
    const int NN = D_ * D_;
    const float* src; _Float16* dh; _Float16* dl; int off;
    if (base < NN) { src = fc_w; dh = fcw_hi; dl = fcw_lo; off = base; }
    else           { src = sal_w; dh = salw_hi; dl = salw_lo; off = base - NN; }
    float4 v = *(const float4*)(src + off);
    float a[4] = {v.x, v.y, v.z, v.w};
    half4 h, lo;
    #pragma unroll
    for (int i = 0; i < 4; ++i) {
        _Float16 hi = (_Float16)a[i];
        h[i] = hi;
        lo[i] = (_Float16)(a[i] - (float)hi);
    }
    *(half4*)(dh + off) = h;
    *(half4*)(dl + off) = lo;
}

// ---------- Kernel 4: transpose + f16 hi/lo split of nov_w ----------
__global__ __launch_bounds__(256) void convert_b(
    const float* __restrict__ B, _Float16* __restrict__ Bt_hi,
    _Float16* __restrict__ Bt_lo)
{
    __shared__ float ld[32][33];
    int k0 = blockIdx.x * 32, n0 = blockIdx.y * 32;
    int r  = threadIdx.x >> 3;
    int c4 = (threadIdx.x & 7) * 4;
    float4 v = *(const float4*)(B + (size_t)(k0 + r) * D_ + n0 + c4);
    ld[r][c4] = v.x; ld[r][c4 + 1] = v.y; ld[r][c4 + 2] = v.z; ld[r][c4 + 3] = v.w;
    __syncthreads();
    half4 h, l;
    #pragma unroll
    for (int i = 0; i < 4; ++i) {
        float x = ld[c4 + i][r];
        _Float16 hi = (_Float16)x;
        h[i] = hi;
        l[i] = (_Float16)(x - (float)hi);
    }
    *(half4*)(Bt_hi + (size_t)(n0 + r) * D_ + k0 + c4) = h;
    *(half4*)(Bt_lo + (size_t)(n0 + r) * D_ + k0 + c4) = l;
}

// ---------- Kernel 5: MFMA 3-pass f16-split GEMM for small GEMMs ----------
template<int EPI>
__global__ __launch_bounds__(256, 2) void gemm_ms(
    const _Float16* __restrict__ Ah, const _Float16* __restrict__ Al,
    const _Float16* __restrict__ Bh, const _Float16* __restrict__ Bl,
    const float* __restrict__ X, float* __restrict__ O,
    _Float16* __restrict__ Oh, _Float16* __restrict__ Ol)
{
    __shared__ _Float16 sAh[128 * 32];
    __shared__ _Float16 sAl[128 * 32];
    __shared__ _Float16 sBh[128 * 32];
    __shared__ _Float16 sBl[128 * 32];

    int tid = threadIdx.x;
    int wave = tid >> 6, lane = tid & 63;
    int n0 = blockIdx.x * 128, m0 = blockIdx.y * 128;
    int wm = (wave >> 1) * 64, wn = (wave & 1) * 64;
    int tm = lane & 15, quad = lane >> 4;

    floatx4 acc[4][4];
    #pragma unroll
    for (int i = 0; i < 4; ++i)
        #pragma unroll
        for (int j = 0; j < 4; ++j)
            acc[i][j] = (floatx4){0.f, 0.f, 0.f, 0.f};

    int grow = lane >> 2;
    int gcol = (lane & 3) * 8;
    const _Float16* pAh = Ah + (size_t)(m0 + wave * 32 + grow) * GK + gcol;
    const _Float16* pAl = Al + (size_t)(m0 + wave * 32 + grow) * GK + gcol;
    const _Float16* pBh = Bh + (size_t)(n0 + wave * 32 + grow) * GK + gcol;
    const _Float16* pBl = Bl + (size_t)(n0 + wave * 32 + grow) * GK + gcol;
    _Float16* lAh = sAh + wave * 32 * 32;
    _Float16* lAl = sAl + wave * 32 * 32;
    _Float16* lBh = sBh + wave * 32 * 32;
    _Float16* lBl = sBl + wave * 32 * 32;

    #pragma unroll 1
    for (int k0 = 0; k0 < GK; k0 += 32) {
        __syncthreads();
        gll16(pAh + k0, lAh);
        gll16(pAh + 16 * GK + k0, lAh + 16 * 32);
        gll16(pAl + k0, lAl);
        gll16(pAl + 16 * GK + k0, lAl + 16 * 32);
        gll16(pBh + k0, lBh);
        gll16(pBh + 16 * GK + k0, lBh + 16 * 32);
        gll16(pBl + k0, lBl);
        gll16(pBl + 16 * GK + k0, lBl + 16 * 32);
        __syncthreads();

        half8 fah[4], fal[4], fbh[4], fbl[4];
        #pragma unroll
        for (int mt = 0; mt < 4; ++mt) {
            int base = (wm + mt * 16 + tm) * 32 + quad * 8;
            fah[mt] = *(const half8*)(sAh + base);
            fal[mt] = *(const half8*)(sAl + base);
        }
        #pragma unroll
        for (int nt = 0; nt < 4; ++nt) {
            int base = (wn + nt * 16 + tm) * 32 + quad * 8;
            fbh[nt] = *(const half8*)(sBh + base);
            fbl[nt] = *(const half8*)(sBl + base);
        }
        #pragma unroll
        for (int mt = 0; mt < 4; ++mt)
            #pragma unroll
            for (int nt = 0; nt < 4; ++nt) {
                acc[mt][nt] = __builtin_amdgcn_mfma_f32_16x16x32_f16(
                    fah[mt], fbh[nt], acc[mt][nt], 0, 0, 0);
                acc[mt][nt] = __builtin_amdgcn_mfma_f32_16x16x32_f16(
                    fah[mt], fbl[nt], acc[mt][nt], 0, 0, 0);
                acc[mt][nt] = __builtin_amdgcn_mfma_f32_16x16x32_f16(
                    fal[mt], fbh[nt], acc[mt][nt], 0, 0, 0);
            }
    }

    #pragma unroll
    for (int mt = 0; mt < 4; ++mt) {
        #pragma unroll
        for (int nt = 0; nt < 4; ++nt) {
            int col = n0 + wn + nt * 16 + tm;
            int rowb = m0 + wm + mt * 16 + quad * 4;
            float xv = X[col];
            #pragma unroll
            for (int r = 0; r < 4; ++r) {
                float v = acc[mt][nt][r];
                if (EPI == 1) {
                    v = tanhf(v + xv);
                    _Float16 hi = (_Float16)v;
                    Oh[(size_t)(rowb + r) * GN + col] = hi;
                    Ol[(size_t)(rowb + r) * GN + col] = (_Float16)(v - (float)hi);
                } else {
                    O[(size_t)(rowb + r) * GN + col] = v + xv;
                }
            }
        }
    }
}

// ---------- Kernel 6: restructured MFMA f16-split GEMM: hWn = sent @ nov_w ----
// A fp32 split on the fly -> LDS double-buffer (LDT=36, uniform banks).
// B streamed global->register (L2-resident, no LDS, no barrier coupling).
// ONE barrier per K-step; all loads issued a full MFMA-block before the drain.
__global__ __launch_bounds__(256, 2) void gemm_hWn(
    const float* __restrict__ A, const _Float16* __restrict__ Bt_hi,
    const _Float16* __restrict__ Bt_lo, float* __restrict__ C)
{
    __shared__ _Float16 As[2][2][128 * LDA];   // [buf][hi/lo]

    int tid  = threadIdx.x;
    int wave = tid >> 6, lane = tid & 63;
    int d = blockIdx.x;
    int islab = d & 7, nblk = (d >> 3) & 7, g = d >> 6;
    int m0 = (g * 8 + islab) * 128;
    int n0 = nblk * 128;
    int wm = (wave >> 1) * 64, wn = (wave & 1) * 64;
    int tm   = lane & 15;
    int quad = lane >> 4;

    floatx4 acc[4][4];
    #pragma unroll
    for (int i = 0; i < 4; ++i)
        #pragma unroll
        for (int j = 0; j < 4; ++j)
            acc[i][j] = (floatx4){0.f, 0.f, 0.f, 0.f};

    // A staging mapping: row sr = tid>>1 (0..127), k-half sh = tid&1
    int sr = tid >> 1, sh = tid & 1;
    const float* Ap = A + (size_t)(m0 + sr) * GK + sh * 16;
    int sbase = sr * LDA + sh * 16;

    // B fragment base: row n0+wn+tm (+nt*16), k offset quad*8
    const _Float16* Bph = Bt_hi + (size_t)(n0 + wn + tm) * GK + quad * 8;
    const _Float16* Bpl = Bt_lo + (size_t)(n0 + wn + tm) * GK + quad * 8;

    auto loadA = [&](int k0, float4& x0, float4& x1, float4& x2, float4& x3) {
        x0 = *(const float4*)(Ap + k0);
        x1 = *(const float4*)(Ap + k0 + 4);
        x2 = *(const float4*)(Ap + k0 + 8);
        x3 = *(const float4*)(Ap + k0 + 12);
    };
    auto writeA = [&](int buf, float4 x0, float4 x1, float4 x2, float4 x3) {
        float af[16] = {x0.x, x0.y, x0.z, x0.w, x1.x, x1.y, x1.z, x1.w,
                        x2.x, x2.y, x2.z, x2.w, x3.x, x3.y, x3.z, x3.w};
        half8 h0, h1, l0, l1;
        #pragma unroll
        for (int i = 0; i < 8; ++i) {
            _Float16 h = (_Float16)af[i];
            h0[i] = h;
            l0[i] = (_Float16)(af[i] - (float)h);
        }
        #pragma unroll
        for (int i = 0; i < 8; ++i) {
            _Float16 h = (_Float16)af[8 + i];
            h1[i] = h;
            l1[i] = (_Float16)(af[8 + i] - (float)h);
        }
        *(half8*)(&As[buf][0][sbase])     = h0;
        *(half8*)(&As[buf][0][sbase + 8]) = h1;
        *(half8*)(&As[buf][1][sbase])     = l0;
        *(half8*)(&As[buf][1][sbase + 8]) = l1;
    };
    auto loadB = [&](int k0, half8* bh, half8* bl) {
        #pragma unroll
        for (int nt = 0; nt < 4; ++nt) {
            bh[nt] = *(const half8*)(Bph + (size_t)(nt * 16) * GK + k0);
            bl[nt] = *(const half8*)(Bpl + (size_t)(nt * 16) * GK + k0);
        }
    };

    half8 bh[4], bl[4], nbh[4], nbl[4];

    // prologue: stage step 0
    {
        float4 x0, x1, x2, x3;
        loadA(0, x0, x1, x2, x3);
        loadB(0, bh, bl);
        writeA(0, x0, x1, x2, x3);
        __syncthreads();
    }

    auto body = [&](int kb, half8* bCh, half8* bCl, half8* bNh, half8* bNl,
                    int knext) {
        bool more = knext < GK;
        float4 y0, y1, y2, y3;
        if (more) {
            loadA(knext, y0, y1, y2, y3);   // fp32 A for next step
            loadB(knext, bNh, bNl);         // B frags for next step
        }
        // fragments from current LDS buffer
        half8 fh[4], fl[4];
        #pragma unroll
        for (int mt = 0; mt < 4; ++mt) {
            int off = (wm + mt * 16 + tm) * LDA + quad * 8;
            fh[mt] = *(const half8*)(&As[kb][0][off]);
            fl[mt] = *(const half8*)(&As[kb][1][off]);
        }
        #pragma unroll
        for (int mt = 0; mt < 4; ++mt)
            #pragma unroll
            for (int nt = 0; nt < 4; ++nt) {
                acc[mt][nt] = __builtin_amdgcn_mfma_f32_16x16x32_f16(
                    fh[mt], bCh[nt], acc[mt][nt], 0, 0, 0);
                acc[mt][nt] = __builtin_amdgcn_mfma_f32_16x16x32_f16(
                    fh[mt], bCl[nt], acc[mt][nt], 0, 0, 0);
                acc[mt][nt] = __builtin_amdgcn_mfma_f32_16x16x32_f16(
                    fl[mt], bCh[nt], acc[mt][nt], 0, 0, 0);
            }
        if (more) writeA(kb ^ 1, y0, y1, y2, y3);
        __syncthreads();
    };

    #pragma unroll 1
    for (int s = 0; s < 32; s += 2) {
        body(0, bh, bl, nbh, nbl, (s + 1) * 32);
        body(1, nbh, nbl, bh, bl, (s + 2) * 32);
    }

    // epilogue: C/D layout col = lane&15, row = quad*4 + reg
    #pragma unroll
    for (int mt = 0; mt < 4; ++mt) {
        #pragma unroll
        for (int nt = 0; nt < 4; ++nt) {
            int col = n0 + wn + nt * 16 + tm;
            int rowb = m0 + wm + mt * 16 + quad * 4;
            #pragma unroll
            for (int r = 0; r < 4; ++r)
                C[(size_t)(rowb + r) * GN + col] = acc[mt][nt][r];
        }
    }
}

// ---------- Kernel 7: scan — one wave per batch, all-register ----------
__global__ __launch_bounds__(64) void scan_kernel(
    const float* __restrict__ sent, const float* __restrict__ hWn,
    const float* __restrict__ u, const float* __restrict__ abs_p,
    const float* __restrict__ rel_vals, const float* __restrict__ bias,
    const int* __restrict__ doc_lens, float* __restrict__ out)
{
    int b = blockIdx.x;
    int lane = threadIdx.x;
    int len = doc_lens[b];
    float lenf = (float)len;

    for (int l = len + lane; l < L_; l += 64) out[b * L_ + l] = 0.f;

    const float* ub = u + (size_t)b * D_ + lane * 4;
    float ur[16], s[16];
    #pragma unroll
    for (int j = 0; j < 4; ++j) {
        *(float4*)(ur + 4 * j) = *(const float4*)(ub + 256 * j);
    }
    #pragma unroll
    for (int i = 0; i < 16; ++i) s[i] = 0.f;

    const float* sb = sent + (size_t)b * L_ * D_ + lane * 4;
    const float* wb = hWn  + (size_t)b * L_ * D_ + lane * 4;
    float biasv = bias[0];

    float hA[16], wA[16], hB[16], wB[16];

    auto loadrow = [&](int row, float* hh, float* ww) {
        const float* ph = sb + (size_t)row * D_;
        const float* pw = wb + (size_t)row * D_;
        #pragma unroll
        for (int j = 0; j < 4; ++j) {
            *(float4*)(hh + 4 * j) = *(const float4*)(ph + 256 * j);
            *(float4*)(ww + 4 * j) = *(const float4*)(pw + 256 * j);
        }
    };

    auto step = [&](int t, const float* hh, const float* ww) {
        float r1 = 0.f, r2 = 0.f;
        #pragma unroll
        for (int i = 0; i < 16; ++i) {
            r1 = fmaf(ww[i], fast_tanh(s[i]), r1);
            r2 = fmaf(hh[i], ur[i], r2);
        }
        #pragma unroll
        for (int off = 32; off; off >>= 1) {
            r1 += __shfl_xor(r1, off);
            r2 += __shfl_xor(r2, off);
        }
        int ridx = (int)rintf((float)(t + 1) * 9.0f / lenf);
        ridx = min(max(ridx, 0), 9);
        float pre = r2 + abs_p[t] + rel_vals[ridx] + biasv - r1;
        float prob = fast_sigmoid(pre);
        if (lane == 0) out[b * L_ + t] = prob;
        #pragma unroll
        for (int i = 0; i < 16; ++i) s[i] = fmaf(prob, hh[i], s[i]);
    };

    loadrow(0, hA, wA);
    int t = 0;
    while (true) {
        int tn = min(t + 1, len - 1);
        loadrow(tn, hB, wB);
        step(t, hA, wA);
        ++t; if (t >= len) break;
        tn = min(t + 1, len - 1);
        loadrow(tn, hA, wA);
        step(t, hB, wB);
        ++t; if (t >= len) break;
    }
}

// ---------- launch ----------
extern "C" void kernel_launch(void* const* d_in, const int* in_sizes, int n_in,
                              void* d_out, int out_size, void* d_ws, size_t ws_size,
                              hipStream_t stream)
{
    const float* sent      = (const float*)d_in[0];
    const float* fc_w      = (const float*)d_in[1];
    const float* fc_b      = (const float*)d_in[2];
    const float* content_w = (const float*)d_in[3];
    const float* sal_w     = (const float*)d_in[4];
    const float* nov_w     = (const float*)d_in[5];
    const float* abs_emb   = (const float*)d_in[6];
    const float* rel_emb   = (const float*)d_in[7];
    const float* abs_w     = (const float*)d_in[8];
    const float* rel_w     = (const float*)d_in[9];
    const float* bias      = (const float*)d_in[10];
    const int*   doc_lens  = (const int*)d_in[11];
    float* out = (float*)d_out;

    char* ws = (char*)d_ws;
    const size_t MB = 1024 * 1024;
    _Float16* docs_hi = (_Float16*)(ws);
    _Float16* docs_lo = (_Float16*)(ws + 1 * MB);
    _Float16* dv_hi   = (_Float16*)(ws + 2 * MB);
    _Float16* dv_lo   = (_Float16*)(ws + 3 * MB);
    float*    u       = (float*)(ws + 4 * MB);
    float*    abs_p   = (float*)(ws + 6 * MB);
    float*    rel_vals= (float*)(ws + 6 * MB + 512);
    _Float16* fcw_hi  = (_Float16*)(ws + 7 * MB);
    _Float16* fcw_lo  = (_Float16*)(ws + 9 * MB);
    _Float16* salw_hi = (_Float16*)(ws + 11 * MB);
    _Float16* salw_lo = (_Float16*)(ws + 13 * MB);
    _Float16* Bt_hi   = (_Float16*)(ws + 15 * MB);
    _Float16* Bt_lo   = (_Float16*)(ws + 17 * MB);
    float*    hWn     = (float*)(ws + 20 * MB);      // 200 MiB

    // 1) docs masked mean + split
    docs_kernel<<<dim3(B_), 256, 0, stream>>>(sent, doc_lens, docs_hi, docs_lo);

    // 2) embedding dots
    emb_kernel<<<dim3(1), 128, 0, stream>>>(abs_emb, rel_emb, abs_w, rel_w, abs_p, rel_vals);

    // 3) split fc_w / sal_w
    wsplit_kernel<<<dim3(2 * D_ * D_ / (256 * 4)), 256, 0, stream>>>(
        fc_w, sal_w, fcw_hi, fcw_lo, salw_hi, salw_lo);

    // 4) transpose + split nov_w
    convert_b<<<dim3(32, 32), 256, 0, stream>>>(nov_w, Bt_hi, Bt_lo);

    // 5) hWn = sent @ nov_w  (XCD-swizzled, single-barrier pipelined K-loop)
    gemm_hWn<<<dim3(3200), 256, 0, stream>>>(sent, Bt_hi, Bt_lo, hWn);

    // 6) doc_vec = tanh(docs @ fc_w^T + fc_b) -> f16 pair
    gemm_ms<1><<<dim3(D_ / 128, B_ / 128), 256, 0, stream>>>(
        docs_hi, docs_lo, fcw_hi, fcw_lo, fc_b, nullptr, dv_hi, dv_lo);

    // 7) u = doc_vec @ sal_w^T + content_w -> fp32
    gemm_ms<2><<<dim3(D_ / 128, B_ / 128), 256, 0, stream>>>(
        dv_hi, dv_lo, salw_hi, salw_lo, content_w, u, nullptr, nullptr);

    // 8) scan: one wave per batch
    scan_kernel<<<dim3(B_), 64, 0, stream>>>(
        sent, hWn, u, abs_p, rel_vals, bias, doc_lens, out);
}

// Round 5
// 802.102 us; speedup vs baseline: 1.2534x; 1.2534x over previous
//
#include <hip/hip_runtime.h>
#include <math.h>

#define B_ 512
#define L_ 100
#define D_ 1024
#define POS_DIM_ 50
#define GM 51200
#define GN 1024
#define GK 1024
#define LDT 40   // padded LDS row stride (halfwords) for A tiles in gemm_hWn

typedef _Float16 half8 __attribute__((ext_vector_type(8)));
typedef _Float16 half4 __attribute__((ext_vector_type(4)));
typedef float floatx4 __attribute__((ext_vector_type(4)));

// ---------- fast device math ----------
__device__ __forceinline__ float fast_tanh(float x) {
    float e = __expf(2.0f * x);
    return 1.0f - 2.0f * __builtin_amdgcn_rcpf(e + 1.0f);
}
__device__ __forceinline__ float fast_sigmoid(float x) {
    return __builtin_amdgcn_rcpf(1.0f + __expf(-x));
}

// async global->LDS, 16B per lane; lds base must be wave-uniform
__device__ __forceinline__ void gll16(const void* g, void* l) {
    __builtin_amdgcn_global_load_lds(
        (const __attribute__((address_space(1))) void*)g,
        (__attribute__((address_space(3))) void*)l, 16, 0, 0);
}

// ---------- Kernel 1: docs (masked mean) + f16 hi/lo split of docs ----------
__global__ __launch_bounds__(256) void docs_kernel(
    const float* __restrict__ sent, const int* __restrict__ doc_lens,
    _Float16* __restrict__ docs_hi, _Float16* __restrict__ docs_lo)
{
    int b = blockIdx.x;
    int tid = threadIdx.x;
    int len = doc_lens[b];
    float inv = 1.0f / (float)len;
    const float* p = sent + (size_t)b * L_ * D_ + tid * 4;
    float4 acc = {0.f, 0.f, 0.f, 0.f};
    for (int l = 0; l < len; ++l) {
        float4 v = *(const float4*)(p + (size_t)l * D_);
        acc.x += v.x; acc.y += v.y; acc.z += v.z; acc.w += v.w;
    }
    float a[4] = {acc.x * inv, acc.y * inv, acc.z * inv, acc.w * inv};
    half4 h, lo;
    #pragma unroll
    for (int i = 0; i < 4; ++i) {
        _Float16 hi = (_Float16)a[i];
        h[i] = hi;
        lo[i] = (_Float16)(a[i] - (float)hi);
    }
    *(half4*)(docs_hi + (size_t)b * D_ + tid * 4) = h;
    *(half4*)(docs_lo + (size_t)b * D_ + tid * 4) = lo;
}

// ---------- Kernel 2: tiny embedding dots ----------
__global__ void emb_kernel(const float* __restrict__ abs_emb,
                           const float* __restrict__ rel_emb,
                           const float* __restrict__ abs_w,
                           const float* __restrict__ rel_w,
                           float* __restrict__ abs_p, float* __restrict__ rel_vals)
{
    int t = threadIdx.x;
    if (t < L_) {
        float a = 0.f;
        for (int j = 0; j < POS_DIM_; ++j) a += abs_emb[t * POS_DIM_ + j] * abs_w[j];
        abs_p[t] = a;
    }
    if (t >= L_ && t < 128) abs_p[t] = 0.f;   // defined values for reg-preload
    if (t < 10) {
        float r = 0.f;
        for (int j = 0; j < POS_DIM_; ++j) r += rel_emb[t * POS_DIM_ + j] * rel_w[j];
        rel_vals[t] = r;
    }
    if (t >= 10 && t < 74) rel_vals[t] = 0.f;  // defined values for reg-preload
}

// ---------- Kernel 3: elementwise f16 hi/lo split of fc_w and sal_w ----------
__global__ __launch_bounds__(256) void wsplit_kernel(
    const float* __restrict__ fc_w, const float* __restrict__ sal_w,
    _Float16* __restrict__ fcw_hi, _Float16* __restrict__ fcw_lo,
    _Float16* __restrict__ salw_hi, _Float16* __restrict__ salw_lo)
{
    int id = blockIdx.x * 256 + threadIdx.x;
    int base = id * 4;
    const int NN = D_ * D_;
    const float* src; _Float16* dh; _Float16* dl; int off;
    if (base < NN) { src = fc_w; dh = fcw_hi; dl = fcw_lo; off = base; }
    else           { src = sal_w; dh = salw_hi; dl = salw_lo; off = base - NN; }
    float4 v = *(const float4*)(src + off);
    float a[4] = {v.x, v.y, v.z, v.w};
    half4 h, lo;
    #pragma unroll
    for (int i = 0; i < 4; ++i) {
        _Float16 hi = (_Float16)a[i];
        h[i] = hi;
        lo[i] = (_Float16)(a[i] - (float)hi);
    }
    *(half4*)(dh + off) = h;
    *(half4*)(dl + off) = lo;
}

// ---------- Kernel 4: transpose + f16 hi/lo split of nov_w ----------
__global__ __launch_bounds__(256) void convert_b(
    const float* __restrict__ B, _Float16* __restrict__ Bt_hi,
    _Float16* __restrict__ Bt_lo)
{
    __shared__ float ld[32][33];
    int k0 = blockIdx.x * 32, n0 = blockIdx.y * 32;
    int r  = threadIdx.x >> 3;
    int c4 = (threadIdx.x & 7) * 4;
    float4 v = *(const float4*)(B + (size_t)(k0 + r) * D_ + n0 + c4);
    ld[r][c4] = v.x; ld[r][c4 + 1] = v.y; ld[r][c4 + 2] = v.z; ld[r][c4 + 3] = v.w;
    __syncthreads();
    half4 h, l;
    #pragma unroll
    for (int i = 0; i < 4; ++i) {
        float x = ld[c4 + i][r];
        _Float16 hi = (_Float16)x;
        h[i] = hi;
        l[i] = (_Float16)(x - (float)hi);
    }
    *(half4*)(Bt_hi + (size_t)(n0 + r) * D_ + k0 + c4) = h;
    *(half4*)(Bt_lo + (size_t)(n0 + r) * D_ + k0 + c4) = l;
}

// ---------- Kernel 5: MFMA 3-pass f16-split GEMM for small GEMMs ----------
template<int EPI>
__global__ __launch_bounds__(256, 2) void gemm_ms(
    const _Float16* __restrict__ Ah, const _Float16* __restrict__ Al,
    const _Float16* __restrict__ Bh, const _Float16* __restrict__ Bl,
    const float* __restrict__ X, float* __restrict__ O,
    _Float16* __restrict__ Oh, _Float16* __restrict__ Ol)
{
    __shared__ _Float16 sAh[128 * 32];
    __shared__ _Float16 sAl[128 * 32];
    __shared__ _Float16 sBh[128 * 32];
    __shared__ _Float16 sBl[128 * 32];

    int tid = threadIdx.x;
    int wave = tid >> 6, lane = tid & 63;
    int n0 = blockIdx.x * 128, m0 = blockIdx.y * 128;
    int wm = (wave >> 1) * 64, wn = (wave & 1) * 64;
    int tm = lane & 15, quad = lane >> 4;

    floatx4 acc[4][4];
    #pragma unroll
    for (int i = 0; i < 4; ++i)
        #pragma unroll
        for (int j = 0; j < 4; ++j)
            acc[i][j] = (floatx4){0.f, 0.f, 0.f, 0.f};

    int grow = lane >> 2;
    int gcol = (lane & 3) * 8;
    const _Float16* pAh = Ah + (size_t)(m0 + wave * 32 + grow) * GK + gcol;
    const _Float16* pAl = Al + (size_t)(m0 + wave * 32 + grow) * GK + gcol;
    const _Float16* pBh = Bh + (size_t)(n0 + wave * 32 + grow) * GK + gcol;
    const _Float16* pBl = Bl + (size_t)(n0 + wave * 32 + grow) * GK + gcol;
    _Float16* lAh = sAh + wave * 32 * 32;
    _Float16* lAl = sAl + wave * 32 * 32;
    _Float16* lBh = sBh + wave * 32 * 32;
    _Float16* lBl = sBl + wave * 32 * 32;

    #pragma unroll 1
    for (int k0 = 0; k0 < GK; k0 += 32) {
        __syncthreads();
        gll16(pAh + k0, lAh);
        gll16(pAh + 16 * GK + k0, lAh + 16 * 32);
        gll16(pAl + k0, lAl);
        gll16(pAl + 16 * GK + k0, lAl + 16 * 32);
        gll16(pBh + k0, lBh);
        gll16(pBh + 16 * GK + k0, lBh + 16 * 32);
        gll16(pBl + k0, lBl);
        gll16(pBl + 16 * GK + k0, lBl + 16 * 32);
        __syncthreads();

        half8 fah[4], fal[4], fbh[4], fbl[4];
        #pragma unroll
        for (int mt = 0; mt < 4; ++mt) {
            int base = (wm + mt * 16 + tm) * 32 + quad * 8;
            fah[mt] = *(const half8*)(sAh + base);
            fal[mt] = *(const half8*)(sAl + base);
        }
        #pragma unroll
        for (int nt = 0; nt < 4; ++nt) {
            int base = (wn + nt * 16 + tm) * 32 + quad * 8;
            fbh[nt] = *(const half8*)(sBh + base);
            fbl[nt] = *(const half8*)(sBl + base);
        }
        #pragma unroll
        for (int mt = 0; mt < 4; ++mt)
            #pragma unroll
            for (int nt = 0; nt < 4; ++nt) {
                acc[mt][nt] = __builtin_amdgcn_mfma_f32_16x16x32_f16(
                    fah[mt], fbh[nt], acc[mt][nt], 0, 0, 0);
                acc[mt][nt] = __builtin_amdgcn_mfma_f32_16x16x32_f16(
                    fah[mt], fbl[nt], acc[mt][nt], 0, 0, 0);
                acc[mt][nt] = __builtin_amdgcn_mfma_f32_16x16x32_f16(
                    fal[mt], fbh[nt], acc[mt][nt], 0, 0, 0);
            }
    }

    #pragma unroll
    for (int mt = 0; mt < 4; ++mt) {
        #pragma unroll
        for (int nt = 0; nt < 4; ++nt) {
            int col = n0 + wn + nt * 16 + tm;
            int rowb = m0 + wm + mt * 16 + quad * 4;
            float xv = X[col];
            #pragma unroll
            for (int r = 0; r < 4; ++r) {
                float v = acc[mt][nt][r];
                if (EPI == 1) {
                    v = tanhf(v + xv);
                    _Float16 hi = (_Float16)v;
                    Oh[(size_t)(rowb + r) * GN + col] = hi;
                    Ol[(size_t)(rowb + r) * GN + col] = (_Float16)(v - (float)hi);
                } else {
                    O[(size_t)(rowb + r) * GN + col] = v + xv;
                }
            }
        }
    }
}

// ---------- Kernel 6: MFMA f16-split GEMM: hWn = sent @ nov_w (R3 version) ----
// A fp32 split on the fly (VALU); B (pre-split) staged via global_load_lds.
// XCD swizzle: d = g*64 + n*8 + i, m = g*8 + i
__global__ __launch_bounds__(256, 2) void gemm_hWn(
    const float* __restrict__ A, const _Float16* __restrict__ Bt_hi,
    const _Float16* __restrict__ Bt_lo, float* __restrict__ C)
{
    __shared__ _Float16 As_hi[128 * LDT];
    __shared__ _Float16 As_lo[128 * LDT];
    __shared__ _Float16 Bs_hi[128 * 32];
    __shared__ _Float16 Bs_lo[128 * 32];

    int tid  = threadIdx.x;
    int wave = tid >> 6, lane = tid & 63;
    int d = blockIdx.x;
    int islab = d & 7, nblk = (d >> 3) & 7, g = d >> 6;
    int m0 = (g * 8 + islab) * 128;
    int n0 = nblk * 128;
    int wm = (wave >> 1) * 64, wn = (wave & 1) * 64;
    int tm   = lane & 15;
    int quad = lane >> 4;

    floatx4 acc[4][4];
    #pragma unroll
    for (int i = 0; i < 4; ++i)
        #pragma unroll
        for (int j = 0; j < 4; ++j)
            acc[i][j] = (floatx4){0.f, 0.f, 0.f, 0.f};

    int sr = tid >> 1;
    int sh = tid & 1;
    const float* Ap = A + (size_t)(m0 + sr) * GK + sh * 16;
    int sbase = sr * LDT + sh * 16;

    int grow = lane >> 2;
    int gcol = (lane & 3) * 8;
    const _Float16* pBh = Bt_hi + (size_t)(n0 + wave * 32 + grow) * GK + gcol;
    const _Float16* pBl = Bt_lo + (size_t)(n0 + wave * 32 + grow) * GK + gcol;
    _Float16* lBh = Bs_hi + wave * 32 * 32;
    _Float16* lBl = Bs_lo + wave * 32 * 32;

    #pragma unroll 1
    for (int k0 = 0; k0 < GK; k0 += 32) {
        float4 a0 = *(const float4*)(Ap + k0);
        float4 a1 = *(const float4*)(Ap + k0 + 4);
        float4 a2 = *(const float4*)(Ap + k0 + 8);
        float4 a3 = *(const float4*)(Ap + k0 + 12);

        half8 ah0, ah1, al0, al1;
        float af[16] = {a0.x, a0.y, a0.z, a0.w, a1.x, a1.y, a1.z, a1.w,
                        a2.x, a2.y, a2.z, a2.w, a3.x, a3.y, a3.z, a3.w};
        #pragma unroll
        for (int i = 0; i < 8; ++i) {
            _Float16 h = (_Float16)af[i];
            ah0[i] = h;
            al0[i] = (_Float16)(af[i] - (float)h);
        }
        #pragma unroll
        for (int i = 0; i < 8; ++i) {
            _Float16 h = (_Float16)af[8 + i];
            ah1[i] = h;
            al1[i] = (_Float16)(af[8 + i] - (float)h);
        }

        __syncthreads();
        gll16(pBh + k0, lBh);
        gll16(pBh + 16 * GK + k0, lBh + 16 * 32);
        gll16(pBl + k0, lBl);
        gll16(pBl + 16 * GK + k0, lBl + 16 * 32);
        *(half8*)(As_hi + sbase)     = ah0;
        *(half8*)(As_hi + sbase + 8) = ah1;
        *(half8*)(As_lo + sbase)     = al0;
        *(half8*)(As_lo + sbase + 8) = al1;
        __syncthreads();

        half8 fa_hi[4], fa_lo[4], fb_hi[4], fb_lo[4];
        #pragma unroll
        for (int mt = 0; mt < 4; ++mt) {
            int row = (wm + mt * 16 + tm) * LDT + quad * 8;
            fa_hi[mt] = *(const half8*)(As_hi + row);
            fa_lo[mt] = *(const half8*)(As_lo + row);
        }
        #pragma unroll
        for (int nt = 0; nt < 4; ++nt) {
            int row = (wn + nt * 16 + tm) * 32 + quad * 8;
            fb_hi[nt] = *(const half8*)(Bs_hi + row);
            fb_lo[nt] = *(const half8*)(Bs_lo + row);
        }
        #pragma unroll
        for (int mt = 0; mt < 4; ++mt)
            #pragma unroll
            for (int nt = 0; nt < 4; ++nt) {
                acc[mt][nt] = __builtin_amdgcn_mfma_f32_16x16x32_f16(
                    fa_hi[mt], fb_hi[nt], acc[mt][nt], 0, 0, 0);
                acc[mt][nt] = __builtin_amdgcn_mfma_f32_16x16x32_f16(
                    fa_hi[mt], fb_lo[nt], acc[mt][nt], 0, 0, 0);
                acc[mt][nt] = __builtin_amdgcn_mfma_f32_16x16x32_f16(
                    fa_lo[mt], fb_hi[nt], acc[mt][nt], 0, 0, 0);
            }
    }

    #pragma unroll
    for (int mt = 0; mt < 4; ++mt) {
        #pragma unroll
        for (int nt = 0; nt < 4; ++nt) {
            int col = n0 + wn + nt * 16 + tm;
            int rowb = m0 + wm + mt * 16 + quad * 4;
            #pragma unroll
            for (int r = 0; r < 4; ++r)
                C[(size_t)(rowb + r) * GN + col] = acc[mt][nt][r];
        }
    }
}

// ---------- Kernel 7: scan — one wave per batch, 4-deep register ring ----------
#define PF 4
__global__ __launch_bounds__(64) void scan_kernel(
    const float* __restrict__ sent, const float* __restrict__ hWn,
    const float* __restrict__ u, const float* __restrict__ abs_p,
    const float* __restrict__ rel_vals, const float* __restrict__ bias,
    const int* __restrict__ doc_lens, float* __restrict__ out)
{
    int b = blockIdx.x;
    int lane = threadIdx.x;
    int len = doc_lens[b];
    float lenf = (float)len;

    for (int l = len + lane; l < L_; l += 64) out[b * L_ + l] = 0.f;

    // constants in registers: abs_p via two lanes-worth, rel_vals via one
    float apA = abs_p[lane];
    float apB = abs_p[64 + lane];         // emb_kernel zero-fills 100..127
    float rvA = rel_vals[lane & 63];      // emb_kernel zero-fills 10..73
    float biasv = bias[0];

    const float* ub = u + (size_t)b * D_ + lane * 4;
    float ur[16], s[16];
    #pragma unroll
    for (int j = 0; j < 4; ++j)
        *(float4*)(ur + 4 * j) = *(const float4*)(ub + 256 * j);
    #pragma unroll
    for (int i = 0; i < 16; ++i) s[i] = 0.f;

    const float* sb = sent + (size_t)b * L_ * D_ + lane * 4;
    const float* wb = hWn  + (size_t)b * L_ * D_ + lane * 4;

    float hbuf[PF][16], wbuf[PF][16];

    auto loadrow = [&](int row, float* hh, float* ww) {
        const float* ph = sb + (size_t)row * D_;
        const float* pw = wb + (size_t)row * D_;
        #pragma unroll
        for (int j = 0; j < 4; ++j) {
            *(float4*)(hh + 4 * j) = *(const float4*)(ph + 256 * j);
            *(float4*)(ww + 4 * j) = *(const float4*)(pw + 256 * j);
        }
    };

    #pragma unroll
    for (int p = 0; p < PF; ++p)
        loadrow(min(p, len - 1), hbuf[p], wbuf[p]);

    int T = (len + PF - 1) & ~(PF - 1);
    #pragma unroll 1
    for (int t0 = 0; t0 < T; t0 += PF) {
        #pragma unroll
        for (int p = 0; p < PF; ++p) {
            int t = t0 + p;
            const float* hh = hbuf[p];
            const float* ww = wbuf[p];

            float r1 = 0.f, r2 = 0.f;
            #pragma unroll
            for (int i = 0; i < 16; ++i) {
                r1 = fmaf(ww[i], fast_tanh(s[i]), r1);
                r2 = fmaf(hh[i], ur[i], r2);
            }
            #pragma unroll
            for (int off = 32; off; off >>= 1) {
                r1 += __shfl_xor(r1, off);
                r2 += __shfl_xor(r2, off);
            }
            int ridx = (int)rintf((float)(t + 1) * 9.0f / lenf);
            ridx = min(max(ridx, 0), 9);
            float ap = (t < 64) ? __shfl(apA, t) : __shfl(apB, t - 64);
            float rv = __shfl(rvA, ridx);
            float pre = r2 + ap + rv + biasv - r1;
            float prob = fast_sigmoid(pre);
            bool valid = t < len;
            if (!valid) prob = 0.f;
            if (valid && lane == 0) out[b * L_ + t] = prob;
            #pragma unroll
            for (int i = 0; i < 16; ++i) s[i] = fmaf(prob, hh[i], s[i]);

            // prefetch row t+PF into this slot (clamped; redundant at tail)
            int tn = t + PF;
            loadrow(tn < len ? tn : len - 1, hbuf[p], wbuf[p]);
        }
    }
}

// ---------- launch ----------
extern "C" void kernel_launch(void* const* d_in, const int* in_sizes, int n_in,
                              void* d_out, int out_size, void* d_ws, size_t ws_size,
                              hipStream_t stream)
{
    const float* sent      = (const float*)d_in[0];
    const float* fc_w      = (const float*)d_in[1];
    const float* fc_b      = (const float*)d_in[2];
    const float* content_w = (const float*)d_in[3];
    const float* sal_w     = (const float*)d_in[4];
    const float* nov_w     = (const float*)d_in[5];
    const float* abs_emb   = (const float*)d_in[6];
    const float* rel_emb   = (const float*)d_in[7];
    const float* abs_w     = (const float*)d_in[8];
    const float* rel_w     = (const float*)d_in[9];
    const float* bias      = (const float*)d_in[10];
    const int*   doc_lens  = (const int*)d_in[11];
    float* out = (float*)d_out;

    char* ws = (char*)d_ws;
    const size_t MB = 1024 * 1024;
    _Float16* docs_hi = (_Float16*)(ws);
    _Float16* docs_lo = (_Float16*)(ws + 1 * MB);
    _Float16* dv_hi   = (_Float16*)(ws + 2 * MB);
    _Float16* dv_lo   = (_Float16*)(ws + 3 * MB);
    float*    u       = (float*)(ws + 4 * MB);
    float*    abs_p   = (float*)(ws + 6 * MB);
    float*    rel_vals= (float*)(ws + 6 * MB + 512);
    _Float16* fcw_hi  = (_Float16*)(ws + 7 * MB);
    _Float16* fcw_lo  = (_Float16*)(ws + 9 * MB);
    _Float16* salw_hi = (_Float16*)(ws + 11 * MB);
    _Float16* salw_lo = (_Float16*)(ws + 13 * MB);
    _Float16* Bt_hi   = (_Float16*)(ws + 15 * MB);
    _Float16* Bt_lo   = (_Float16*)(ws + 17 * MB);
    float*    hWn     = (float*)(ws + 20 * MB);      // 200 MiB

    // 1) docs masked mean + split
    docs_kernel<<<dim3(B_), 256, 0, stream>>>(sent, doc_lens, docs_hi, docs_lo);

    // 2) embedding dots (+ zero-fill padding for scan's register preload)
    emb_kernel<<<dim3(1), 128, 0, stream>>>(abs_emb, rel_emb, abs_w, rel_w, abs_p, rel_vals);

    // 3) split fc_w / sal_w
    wsplit_kernel<<<dim3(2 * D_ * D_ / (256 * 4)), 256, 0, stream>>>(
        fc_w, sal_w, fcw_hi, fcw_lo, salw_hi, salw_lo);

    // 4) transpose + split nov_w
    convert_b<<<dim3(32, 32), 256, 0, stream>>>(nov_w, Bt_hi, Bt_lo);

    // 5) hWn = sent @ nov_w  (R3 structure, XCD-swizzled)
    gemm_hWn<<<dim3(3200), 256, 0, stream>>>(sent, Bt_hi, Bt_lo, hWn);

    // 6) doc_vec = tanh(docs @ fc_w^T + fc_b) -> f16 pair
    gemm_ms<1><<<dim3(D_ / 128, B_ / 128), 256, 0, stream>>>(
        docs_hi, docs_lo, fcw_hi, fcw_lo, fc_b, nullptr, dv_hi, dv_lo);

    // 7) u = doc_vec @ sal_w^T + content_w -> fp32
    gemm_ms<2><<<dim3(D_ / 128, B_ / 128), 256, 0, stream>>>(
        dv_hi, dv_lo, salw_hi, salw_lo, content_w, u, nullptr, nullptr);

    // 8) scan: one wave per batch, 4-deep ring prefetch
    scan_kernel<<<dim3(B_), 64, 0, stream>>>(
        sent, hWn, u, abs_p, rel_vals, bias, doc_lens, out);
}